// Round 4
// baseline (456.112 us; speedup 1.0000x reference)
//
#include <hip/hip_runtime.h>
#include <hip/hip_fp16.h>

#define NN 100000
#define SCAN_B 256

// ---------------- degree histogram (int) ----------------
__global__ void hist_kernel(const int* __restrict__ dst, int* __restrict__ degcnt, int E) {
    int e = blockIdx.x * blockDim.x + threadIdx.x;
    if (e < E) atomicAdd(&degcnt[dst[e]], 1);
}

__global__ void dis_kernel(const int* __restrict__ degcnt, float* __restrict__ dis, int N) {
    int i = blockIdx.x * blockDim.x + threadIdx.x;
    if (i < N) dis[i] = rsqrtf((float)degcnt[i] + 1.0f);  // + self loop
}

// ---------------- exclusive prefix scan over degcnt -> row_start ----------------
__global__ void scan1_kernel(const int* __restrict__ degcnt, int* __restrict__ row_start,
                             int* __restrict__ blk_sums, int N) {
    __shared__ int sm[SCAN_B];
    int t = threadIdx.x, i = blockIdx.x * SCAN_B + t;
    int v = (i < N) ? degcnt[i] : 0;
    sm[t] = v; __syncthreads();
    for (int off = 1; off < SCAN_B; off <<= 1) {
        int x = (t >= off) ? sm[t - off] : 0; __syncthreads();
        sm[t] += x; __syncthreads();
    }
    if (i < N) row_start[i] = sm[t] - v;
    if (t == SCAN_B - 1) blk_sums[blockIdx.x] = sm[t];
}

__global__ void scan2_kernel(const int* __restrict__ blk_sums, int* __restrict__ blk_off, int nblk) {
    __shared__ int sm[SCAN_B];
    __shared__ int run;
    int t = threadIdx.x;
    if (t == 0) run = 0;
    __syncthreads();
    for (int base = 0; base < nblk; base += SCAN_B) {
        int i = base + t;
        int v = (i < nblk) ? blk_sums[i] : 0;
        sm[t] = v; __syncthreads();
        for (int off = 1; off < SCAN_B; off <<= 1) {
            int x = (t >= off) ? sm[t - off] : 0; __syncthreads();
            sm[t] += x; __syncthreads();
        }
        if (i < nblk) blk_off[i] = run + sm[t] - v;
        __syncthreads();
        if (t == 0) run += sm[SCAN_B - 1];
        __syncthreads();
    }
}

__global__ void scan3_kernel(int* __restrict__ row_start, const int* __restrict__ blk_off, int N, int E) {
    int i = blockIdx.x * SCAN_B + threadIdx.x;
    if (i < N) row_start[i] += blk_off[blockIdx.x];
}

// ---------------- CSR fill: consumes row_start (becomes row-end array) ----------------
__global__ void fill_kernel(const int* __restrict__ src, const int* __restrict__ dst,
                            int* __restrict__ row_cursor, int* __restrict__ csr_src, int E) {
    int e = blockIdx.x * blockDim.x + threadIdx.x;
    if (e >= E) return;
    int pos = atomicAdd(&row_cursor[dst[e]], 1);
    csr_src[pos] = src[e];
}

// ---------------- fp32 -> fp16 table with dis premultiplied: tab[i][c] = x[i][c]*dis[i] ----------------
__global__ void cvt_kernel(const float* __restrict__ in, const float* __restrict__ dis,
                           __half* __restrict__ out, long long n4) {
    long long i = (long long)blockIdx.x * blockDim.x + threadIdx.x;
    if (i >= n4) return;
    float4 v = ((const float4*)in)[i];
    float w = dis[(int)(i >> 4)];   // 16 float4-chunks per 64-col row
    __half2* o = (__half2*)out;
    o[2 * i]     = __floats2half2_rn(v.x * w, v.y * w);
    o[2 * i + 1] = __floats2half2_rn(v.z * w, v.w * w);
}

// ---------------- GEMM: h[N,F] = x[N,K] @ W[K,F] (+bias+relu) or (*dis[row] -> fp16) ----------------
template<int K, int F, int ROWS, bool BIASRELU, typename OutT>
__global__ __launch_bounds__(256) void gemm_kernel(const float* __restrict__ x,
                                                   const float* __restrict__ W,
                                                   const float* __restrict__ bias,
                                                   const float* __restrict__ dis,
                                                   OutT* __restrict__ h, int N) {
    __shared__ float sW[K * F];
    __shared__ float sX[ROWS * K];
    const int tid = threadIdx.x;
    for (int i = tid; i < K * F; i += 256) sW[i] = W[i];
    const int row0 = blockIdx.x * ROWS;
    const int nrows = min(ROWS, N - row0);
    for (int i = tid; i < nrows * K; i += 256) sX[i] = x[(size_t)row0 * K + i];
    __syncthreads();
    const int col = tid % F;
    for (int rr = tid / F; rr < nrows; rr += 256 / F) {
        float acc = 0.0f;
        #pragma unroll
        for (int k = 0; k < K; ++k) acc += sX[rr * K + k] * sW[k * F + col];
        size_t idx = (size_t)(row0 + rr) * F + col;
        if constexpr (sizeof(OutT) == 2) {
            h[idx] = __float2half(acc * dis[row0 + rr]);
        } else {
            if (BIASRELU) acc = fmaxf(acc + bias[col], 0.0f);
            h[idx] = acc;
        }
    }
}

// ---------------- gather: out[d] = dis[d]*(tab[d] + sum_{s in nbrs(d)} tab[s]) (+b) ----------------
// ends[] = row_start after fill consumption: row d spans [ends[d-1], ends[d]), ends[-1]=0
template<bool BIAS>
__global__ __launch_bounds__(256) void gather64_kernel(const __half* __restrict__ tab,
                                                       const float* __restrict__ dis,
                                                       const float* __restrict__ b,
                                                       const int* __restrict__ ends,
                                                       const int* __restrict__ csr_src,
                                                       float* __restrict__ out, int N) {
    const int node = blockIdx.x * 4 + (threadIdx.x >> 6);
    const int lane = threadIdx.x & 63;
    if (node >= N) return;
    const int beg = (node == 0) ? 0 : ends[node - 1];
    const int end = ends[node];
    float acc = __half2float(tab[(size_t)node * 64 + lane]);  // self loop (tab has dis[s] folded)
    int j = beg;
    for (; j + 3 < end; j += 4) {
        int s0 = csr_src[j],     s1 = csr_src[j + 1];
        int s2 = csr_src[j + 2], s3 = csr_src[j + 3];
        float v0 = __half2float(tab[(size_t)s0 * 64 + lane]);
        float v1 = __half2float(tab[(size_t)s1 * 64 + lane]);
        float v2 = __half2float(tab[(size_t)s2 * 64 + lane]);
        float v3 = __half2float(tab[(size_t)s3 * 64 + lane]);
        acc += v0; acc += v1; acc += v2; acc += v3;
    }
    for (; j < end; ++j) acc += __half2float(tab[(size_t)csr_src[j] * 64 + lane]);
    acc *= dis[node];
    if (BIAS) acc += b[lane];
    out[(size_t)node * 64 + lane] = acc;
}

extern "C" void kernel_launch(void* const* d_in, const int* in_sizes, int n_in,
                              void* d_out, int out_size, void* d_ws, size_t ws_size,
                              hipStream_t stream) {
    const float* x  = (const float*)d_in[0];
    const int*   ei = (const int*)d_in[1];
    const float* W1 = (const float*)d_in[2];
    const float* b1 = (const float*)d_in[3];
    const float* W2 = (const float*)d_in[4];
    const float* b2 = (const float*)d_in[5];
    float* out = (float*)d_out;

    const int N = NN;
    const int E = in_sizes[1] / 2;
    const int* src = ei;
    const int* dst = ei + E;
    const int nblk = (N + SCAN_B - 1) / SCAN_B;

    // workspace layout (4-byte words)
    float* ws = (float*)d_ws;
    float*  dis       = ws;                                   // N
    int*    degcnt    = (int*)(ws + N);                       // N
    int*    row_start = (int*)(ws + 2 * N);                   // N (consumed -> ends)
    int*    blk_sums  = (int*)(ws + 3 * N);                   // <=1024
    int*    blk_off   = (int*)(ws + 3 * N + 1024);            // <=1024
    int*    csr_src   = (int*)(ws + 3 * N + 2048);            // E
    float*  base      = ws + 3 * N + 2048 + (size_t)E;
    __half* xh        = (__half*)base;                        // N*64 halves = N*32 words
    __half* zh        = (__half*)(base + (size_t)N * 32);     // N*64 halves = N*32 words
    float*  agg       = base + (size_t)N * 64;                // N*64 floats
    float*  h1        = agg + (size_t)N * 64;                 // N*128 floats

    // ---- degree + CSR build ----
    hipMemsetAsync(degcnt, 0, (size_t)N * sizeof(int), stream);
    hist_kernel<<<(E + 255) / 256, 256, 0, stream>>>(dst, degcnt, E);
    dis_kernel<<<(N + 255) / 256, 256, 0, stream>>>(degcnt, dis, N);
    scan1_kernel<<<nblk, SCAN_B, 0, stream>>>(degcnt, row_start, blk_sums, N);
    scan2_kernel<<<1, SCAN_B, 0, stream>>>(blk_sums, blk_off, nblk);
    scan3_kernel<<<nblk, SCAN_B, 0, stream>>>(row_start, blk_off, N, E);
    fill_kernel<<<(E + 255) / 256, 256, 0, stream>>>(src, dst, row_start, csr_src, E);

    // ---- layer 1: xh = dis*x (fp16), agg = A_hat-gather, h1 = relu(agg@W1 + b1) ----
    {
        long long n4 = (long long)N * 64 / 4;
        cvt_kernel<<<(int)((n4 + 255) / 256), 256, 0, stream>>>(x, dis, xh, n4);
    }
    gather64_kernel<false><<<(N + 3) / 4, 256, 0, stream>>>(xh, dis, nullptr, row_start, csr_src, agg, N);
    gemm_kernel<64, 128, 32, true, float><<<(N + 31) / 32, 256, 0, stream>>>(agg, W1, b1, nullptr, h1, N);

    // ---- layer 2: zh = (h1@W2)*dis (fp16), out = A_hat-gather + b2 ----
    gemm_kernel<128, 64, 16, false, __half><<<(N + 15) / 16, 256, 0, stream>>>(h1, W2, nullptr, dis, zh, N);
    gather64_kernel<true><<<(N + 3) / 4, 256, 0, stream>>>(zh, dis, b2, row_start, csr_src, out, N);
}

// Round 5
// 311.202 us; speedup vs baseline: 1.4656x; 1.4656x over previous
//
#include <hip/hip_runtime.h>
#include <hip/hip_fp16.h>

#define NN 100000
#define NB 391        // ceil(NN/256) buckets of 256 dst nodes
#define NG 256        // edge-pass blocks
#define SCAN_B 256

// ---------------- pass A: per-block bucket histogram (LDS) ----------------
__global__ __launch_bounds__(256) void bhist_kernel(const int* __restrict__ dst,
                                                    int* __restrict__ counts, int E) {
    __shared__ int h[NB];
    for (int i = threadIdx.x; i < NB; i += 256) h[i] = 0;
    __syncthreads();
    const int chunk = (E + NG - 1) / NG;
    const int lo = blockIdx.x * chunk, hi = min(E, lo + chunk);
    for (int e = lo + threadIdx.x; e < hi; e += 256) atomicAdd(&h[dst[e] >> 8], 1);
    __syncthreads();
    for (int i = threadIdx.x; i < NB; i += 256) counts[i * NG + blockIdx.x] = h[i];
}

// ---------------- in-place exclusive scan over counts[M] ----------------
__global__ void scan1_kernel(int* __restrict__ a, int* __restrict__ blk_sums, int M) {
    __shared__ int sm[SCAN_B];
    int t = threadIdx.x, i = blockIdx.x * SCAN_B + t;
    int v = (i < M) ? a[i] : 0;
    sm[t] = v; __syncthreads();
    for (int off = 1; off < SCAN_B; off <<= 1) {
        int x = (t >= off) ? sm[t - off] : 0; __syncthreads();
        sm[t] += x; __syncthreads();
    }
    if (i < M) a[i] = sm[t] - v;
    if (t == SCAN_B - 1) blk_sums[blockIdx.x] = sm[t];
}

__global__ void scan2_kernel(const int* __restrict__ blk_sums, int* __restrict__ blk_off, int nblk) {
    __shared__ int sm[SCAN_B];
    __shared__ int run;
    int t = threadIdx.x;
    if (t == 0) run = 0;
    __syncthreads();
    for (int base = 0; base < nblk; base += SCAN_B) {
        int i = base + t;
        int v = (i < nblk) ? blk_sums[i] : 0;
        sm[t] = v; __syncthreads();
        for (int off = 1; off < SCAN_B; off <<= 1) {
            int x = (t >= off) ? sm[t - off] : 0; __syncthreads();
            sm[t] += x; __syncthreads();
        }
        if (i < nblk) blk_off[i] = run + sm[t] - v;
        __syncthreads();
        if (t == 0) run += sm[SCAN_B - 1];
        __syncthreads();
    }
}

__global__ void scan3_kernel(int* __restrict__ a, const int* __restrict__ blk_off, int M) {
    int i = blockIdx.x * SCAN_B + threadIdx.x;
    if (i < M) a[i] += blk_off[blockIdx.x];
}

// ---------------- pass C: scatter edges into bucket-contiguous staging ----------------
// staging word = src | (dst_local << 17)   (src < 2^17, dst_local < 256)
__global__ __launch_bounds__(256) void bscatter_kernel(const int* __restrict__ src,
                                                       const int* __restrict__ dst,
                                                       const int* __restrict__ cstart,
                                                       int* __restrict__ staging, int E) {
    __shared__ int cur[NB];
    for (int i = threadIdx.x; i < NB; i += 256) cur[i] = cstart[i * NG + blockIdx.x];
    __syncthreads();
    const int chunk = (E + NG - 1) / NG;
    const int lo = blockIdx.x * chunk, hi = min(E, lo + chunk);
    for (int e = lo + threadIdx.x; e < hi; e += 256) {
        int d = dst[e];
        int pos = atomicAdd(&cur[d >> 8], 1);
        staging[pos] = src[e] | ((d & 255) << 17);
    }
}

// ---------------- pass D: per-bucket CSR finalize + row_start + dis ----------------
__global__ __launch_bounds__(256) void bfinal_kernel(const int* __restrict__ cstart,
                                                     const int* __restrict__ staging,
                                                     int* __restrict__ csr_src,
                                                     int* __restrict__ row_start,
                                                     float* __restrict__ dis, int N, int E) {
    __shared__ int h[256];
    __shared__ int sc[256];
    __shared__ int cur[256];
    const int b = blockIdx.x, t = threadIdx.x;
    const int base = cstart[b * NG];
    const int endb = (b == NB - 1) ? E : cstart[(b + 1) * NG];
    h[t] = 0; __syncthreads();
    for (int i = base + t; i < endb; i += 256) atomicAdd(&h[staging[i] >> 17], 1);
    __syncthreads();
    int v = h[t];
    sc[t] = v; __syncthreads();
    for (int off = 1; off < 256; off <<= 1) {
        int x = (t >= off) ? sc[t - off] : 0; __syncthreads();
        sc[t] += x; __syncthreads();
    }
    int excl = sc[t] - v;
    cur[t] = base + excl;
    int node = b * 256 + t;
    if (node < N) {
        row_start[node] = base + excl;
        dis[node] = rsqrtf((float)v + 1.0f);
    }
    if (b == NB - 1 && t == 0) row_start[N] = E;
    __syncthreads();
    for (int i = base + t; i < endb; i += 256) {
        int p = staging[i];
        int pos = atomicAdd(&cur[p >> 17], 1);
        csr_src[pos] = p & 0x1FFFF;
    }
}

// ---------------- fp32 -> fp16 table with dis premultiplied ----------------
__global__ void cvt_kernel(const float* __restrict__ in, const float* __restrict__ dis,
                           __half* __restrict__ out, long long n4) {
    long long i = (long long)blockIdx.x * blockDim.x + threadIdx.x;
    if (i >= n4) return;
    float4 v = ((const float4*)in)[i];
    float w = dis[(int)(i >> 4)];
    __half2* o = (__half2*)out;
    o[2 * i]     = __floats2half2_rn(v.x * w, v.y * w);
    o[2 * i + 1] = __floats2half2_rn(v.z * w, v.w * w);
}

// ---------------- GEMM: h[N,F] = x[N,K] @ W[K,F] (+bias+relu) or (*dis -> fp16) ----------------
template<int K, int F, int ROWS, bool BIASRELU, typename OutT>
__global__ __launch_bounds__(256) void gemm_kernel(const float* __restrict__ x,
                                                   const float* __restrict__ W,
                                                   const float* __restrict__ bias,
                                                   const float* __restrict__ dis,
                                                   OutT* __restrict__ h, int N) {
    __shared__ float sW[K * F];
    __shared__ float sX[ROWS * K];
    const int tid = threadIdx.x;
    for (int i = tid; i < K * F; i += 256) sW[i] = W[i];
    const int row0 = blockIdx.x * ROWS;
    const int nrows = min(ROWS, N - row0);
    for (int i = tid; i < nrows * K; i += 256) sX[i] = x[(size_t)row0 * K + i];
    __syncthreads();
    const int col = tid % F;
    for (int rr = tid / F; rr < nrows; rr += 256 / F) {
        float acc = 0.0f;
        #pragma unroll
        for (int k = 0; k < K; ++k) acc += sX[rr * K + k] * sW[k * F + col];
        size_t idx = (size_t)(row0 + rr) * F + col;
        if constexpr (sizeof(OutT) == 2) {
            h[idx] = __float2half(acc * dis[row0 + rr]);
        } else {
            if (BIASRELU) acc = fmaxf(acc + bias[col], 0.0f);
            h[idx] = acc;
        }
    }
}

// ---------------- gather: out[d] = dis[d]*(tab[d] + sum_{s in nbrs(d)} tab[s]) (+b) ----------------
template<bool BIAS>
__global__ __launch_bounds__(256) void gather64_kernel(const __half* __restrict__ tab,
                                                       const float* __restrict__ dis,
                                                       const float* __restrict__ b,
                                                       const int* __restrict__ row_start,
                                                       const int* __restrict__ csr_src,
                                                       float* __restrict__ out, int N) {
    const int node = blockIdx.x * 4 + (threadIdx.x >> 6);
    const int lane = threadIdx.x & 63;
    if (node >= N) return;
    const int beg = row_start[node], end = row_start[node + 1];
    float acc = __half2float(tab[(size_t)node * 64 + lane]);  // self loop (dis[s] folded in tab)
    float acc2 = 0.0f;
    int j = beg;
    for (; j + 7 < end; j += 8) {
        int s0 = csr_src[j],     s1 = csr_src[j + 1];
        int s2 = csr_src[j + 2], s3 = csr_src[j + 3];
        int s4 = csr_src[j + 4], s5 = csr_src[j + 5];
        int s6 = csr_src[j + 6], s7 = csr_src[j + 7];
        float v0 = __half2float(tab[(size_t)s0 * 64 + lane]);
        float v1 = __half2float(tab[(size_t)s1 * 64 + lane]);
        float v2 = __half2float(tab[(size_t)s2 * 64 + lane]);
        float v3 = __half2float(tab[(size_t)s3 * 64 + lane]);
        float v4 = __half2float(tab[(size_t)s4 * 64 + lane]);
        float v5 = __half2float(tab[(size_t)s5 * 64 + lane]);
        float v6 = __half2float(tab[(size_t)s6 * 64 + lane]);
        float v7 = __half2float(tab[(size_t)s7 * 64 + lane]);
        acc += v0; acc2 += v1; acc += v2; acc2 += v3;
        acc += v4; acc2 += v5; acc += v6; acc2 += v7;
    }
    for (; j < end; ++j) acc += __half2float(tab[(size_t)csr_src[j] * 64 + lane]);
    acc = (acc + acc2) * dis[node];
    if (BIAS) acc += b[lane];
    out[(size_t)node * 64 + lane] = acc;
}

extern "C" void kernel_launch(void* const* d_in, const int* in_sizes, int n_in,
                              void* d_out, int out_size, void* d_ws, size_t ws_size,
                              hipStream_t stream) {
    const float* x  = (const float*)d_in[0];
    const int*   ei = (const int*)d_in[1];
    const float* W1 = (const float*)d_in[2];
    const float* b1 = (const float*)d_in[3];
    const float* W2 = (const float*)d_in[4];
    const float* b2 = (const float*)d_in[5];
    float* out = (float*)d_out;

    const int N = NN;
    const int E = in_sizes[1] / 2;
    const int* src = ei;
    const int* dst = ei + E;
    const int M = NB * NG;                       // 100096 counts
    const int scan_blocks = (M + SCAN_B - 1) / SCAN_B;

    // workspace layout (4-byte words)
    int* counts    = (int*)d_ws;                 // M (scanned in place -> cstart)
    int* blk_sums  = counts + M;                 // 1024
    int* blk_off   = blk_sums + 1024;            // 1024
    int* row_start = blk_off + 1024;             // N+1 (+pad)
    float* dis     = (float*)(row_start + N + 64);  // N
    int* staging   = (int*)(dis + N);            // E
    int* csr_src   = staging + E;                // E
    float* base    = (float*)(csr_src + E);
    __half* xh     = (__half*)base;              // N*64 halves
    __half* zh     = (__half*)(base + (size_t)N * 32);
    float* agg     = base + (size_t)N * 64;      // N*64
    float* h1      = agg + (size_t)N * 64;       // N*128

    // ---- CSR build (bucketed, no global atomics except LDS) ----
    bhist_kernel<<<NG, 256, 0, stream>>>(dst, counts, E);
    scan1_kernel<<<scan_blocks, SCAN_B, 0, stream>>>(counts, blk_sums, M);
    scan2_kernel<<<1, SCAN_B, 0, stream>>>(blk_sums, blk_off, scan_blocks);
    scan3_kernel<<<scan_blocks, SCAN_B, 0, stream>>>(counts, blk_off, M);
    bscatter_kernel<<<NG, 256, 0, stream>>>(src, dst, counts, staging, E);
    bfinal_kernel<<<NB, 256, 0, stream>>>(counts, staging, csr_src, row_start, dis, N, E);

    // ---- layer 1: xh = dis*x (fp16), agg = A_hat-gather, h1 = relu(agg@W1 + b1) ----
    {
        long long n4 = (long long)N * 64 / 4;
        cvt_kernel<<<(int)((n4 + 255) / 256), 256, 0, stream>>>(x, dis, xh, n4);
    }
    gather64_kernel<false><<<(N + 3) / 4, 256, 0, stream>>>(xh, dis, nullptr, row_start, csr_src, agg, N);
    gemm_kernel<64, 128, 32, true, float><<<(N + 31) / 32, 256, 0, stream>>>(agg, W1, b1, nullptr, h1, N);

    // ---- layer 2: zh = (h1@W2)*dis (fp16), out = A_hat-gather + b2 ----
    gemm_kernel<128, 64, 16, false, __half><<<(N + 15) / 16, 256, 0, stream>>>(h1, W2, nullptr, dis, zh, N);
    gather64_kernel<true><<<(N + 3) / 4, 256, 0, stream>>>(zh, dis, b2, row_start, csr_src, out, N);
}

// Round 6
// 238.144 us; speedup vs baseline: 1.9153x; 1.3068x over previous
//
#include <hip/hip_runtime.h>
#include <hip/hip_fp16.h>

#define NN 100000
#define NB 391        // ceil(NN/256) buckets of 256 dst nodes
#define NG 256        // edge-pass blocks
#define SCAN_B 256

using f16x8 = __attribute__((ext_vector_type(8))) _Float16;
using f32x4 = __attribute__((ext_vector_type(4))) float;

// ---------------- pass A: per-block bucket histogram (LDS) ----------------
__global__ __launch_bounds__(256) void bhist_kernel(const int* __restrict__ dst,
                                                    int* __restrict__ counts, int E) {
    __shared__ int h[NB];
    for (int i = threadIdx.x; i < NB; i += 256) h[i] = 0;
    __syncthreads();
    const int chunk = (E + NG - 1) / NG;
    const int lo = blockIdx.x * chunk, hi = min(E, lo + chunk);
    for (int e = lo + threadIdx.x; e < hi; e += 256) atomicAdd(&h[dst[e] >> 8], 1);
    __syncthreads();
    for (int i = threadIdx.x; i < NB; i += 256) counts[i * NG + blockIdx.x] = h[i];
}

// ---------------- in-place exclusive scan over counts[M] ----------------
__global__ void scan1_kernel(int* __restrict__ a, int* __restrict__ blk_sums, int M) {
    __shared__ int sm[SCAN_B];
    int t = threadIdx.x, i = blockIdx.x * SCAN_B + t;
    int v = (i < M) ? a[i] : 0;
    sm[t] = v; __syncthreads();
    for (int off = 1; off < SCAN_B; off <<= 1) {
        int x = (t >= off) ? sm[t - off] : 0; __syncthreads();
        sm[t] += x; __syncthreads();
    }
    if (i < M) a[i] = sm[t] - v;
    if (t == SCAN_B - 1) blk_sums[blockIdx.x] = sm[t];
}

__global__ void scan2_kernel(const int* __restrict__ blk_sums, int* __restrict__ blk_off, int nblk) {
    __shared__ int sm[SCAN_B];
    __shared__ int run;
    int t = threadIdx.x;
    if (t == 0) run = 0;
    __syncthreads();
    for (int base = 0; base < nblk; base += SCAN_B) {
        int i = base + t;
        int v = (i < nblk) ? blk_sums[i] : 0;
        sm[t] = v; __syncthreads();
        for (int off = 1; off < SCAN_B; off <<= 1) {
            int x = (t >= off) ? sm[t - off] : 0; __syncthreads();
            sm[t] += x; __syncthreads();
        }
        if (i < nblk) blk_off[i] = run + sm[t] - v;
        __syncthreads();
        if (t == 0) run += sm[SCAN_B - 1];
        __syncthreads();
    }
}

__global__ void scan3_kernel(int* __restrict__ a, const int* __restrict__ blk_off, int M) {
    int i = blockIdx.x * SCAN_B + threadIdx.x;
    if (i < M) a[i] += blk_off[blockIdx.x];
}

// ---------------- pass C: scatter edges into bucket-contiguous staging ----------------
__global__ __launch_bounds__(256) void bscatter_kernel(const int* __restrict__ src,
                                                       const int* __restrict__ dst,
                                                       const int* __restrict__ cstart,
                                                       int* __restrict__ staging, int E) {
    __shared__ int cur[NB];
    for (int i = threadIdx.x; i < NB; i += 256) cur[i] = cstart[i * NG + blockIdx.x];
    __syncthreads();
    const int chunk = (E + NG - 1) / NG;
    const int lo = blockIdx.x * chunk, hi = min(E, lo + chunk);
    for (int e = lo + threadIdx.x; e < hi; e += 256) {
        int d = dst[e];
        int pos = atomicAdd(&cur[d >> 8], 1);
        staging[pos] = src[e] | ((d & 255) << 17);
    }
}

// ---------------- pass D: per-bucket CSR finalize + row_start + dis ----------------
__global__ __launch_bounds__(256) void bfinal_kernel(const int* __restrict__ cstart,
                                                     const int* __restrict__ staging,
                                                     int* __restrict__ csr_src,
                                                     int* __restrict__ row_start,
                                                     float* __restrict__ dis, int N, int E) {
    __shared__ int h[256];
    __shared__ int sc[256];
    __shared__ int cur[256];
    const int b = blockIdx.x, t = threadIdx.x;
    const int base = cstart[b * NG];
    const int endb = (b == NB - 1) ? E : cstart[(b + 1) * NG];
    h[t] = 0; __syncthreads();
    for (int i = base + t; i < endb; i += 256) atomicAdd(&h[staging[i] >> 17], 1);
    __syncthreads();
    int v = h[t];
    sc[t] = v; __syncthreads();
    for (int off = 1; off < 256; off <<= 1) {
        int x = (t >= off) ? sc[t - off] : 0; __syncthreads();
        sc[t] += x; __syncthreads();
    }
    int excl = sc[t] - v;
    cur[t] = base + excl;
    int node = b * 256 + t;
    if (node < N) {
        row_start[node] = base + excl;
        dis[node] = rsqrtf((float)v + 1.0f);
    }
    if (b == NB - 1 && t == 0) row_start[N] = E;
    __syncthreads();
    for (int i = base + t; i < endb; i += 256) {
        int p = staging[i];
        int pos = atomicAdd(&cur[p >> 17], 1);
        csr_src[pos] = p & 0x1FFFF;
    }
}

// ---------------- fp32 -> fp16 table with dis premultiplied ----------------
__global__ void cvt_kernel(const float* __restrict__ in, const float* __restrict__ dis,
                           __half* __restrict__ out, long long n4) {
    long long i = (long long)blockIdx.x * blockDim.x + threadIdx.x;
    if (i >= n4) return;
    float4 v = ((const float4*)in)[i];
    float w = dis[(int)(i >> 4)];
    __half2* o = (__half2*)out;
    o[2 * i]     = __floats2half2_rn(v.x * w, v.y * w);
    o[2 * i + 1] = __floats2half2_rn(v.z * w, v.w * w);
}

// ---------------- W[K,F] fp32 -> Wt[F,K] fp16 ----------------
template<int K, int F>
__global__ void cvtWt_kernel(const float* __restrict__ W, __half* __restrict__ Wt) {
    int i = blockIdx.x * 256 + threadIdx.x;
    if (i >= K * F) return;
    int k = i / F, c = i % F;
    Wt[c * K + k] = __float2half(W[i]);
}

// ---------------- MFMA GEMM: C[N,F](fp16) = A[N,K](fp16) @ Wt[F,K]^T, epilogue ----------------
// EPI 0: relu(acc + bias[col]); EPI 1: acc * dis[row]
template<int K, int F, int EPI>
__global__ __launch_bounds__(256) void gemm_mfma_kernel(const __half* __restrict__ A,
                                                        const __half* __restrict__ Wt,
                                                        const float* __restrict__ bias,
                                                        const float* __restrict__ dis,
                                                        __half* __restrict__ C, int N) {
    constexpr int BM = 32;
    constexpr int NT = F / 32;              // n-tiles per wave (wave covers F/2 cols)
    const int wid  = threadIdx.x >> 6;
    const int lane = threadIdx.x & 63;
    const int wr = wid >> 1;                // 0..1
    const int wc = wid & 1;                 // 0..1
    const int row0 = blockIdx.x * BM + wr * 16;
    const int col0 = wc * (F / 2);
    const int lrow = lane & 15;
    const int kgrp = lane >> 4;

    f32x4 acc[NT];
    #pragma unroll
    for (int nt = 0; nt < NT; ++nt) acc[nt] = (f32x4){0.f, 0.f, 0.f, 0.f};

    #pragma unroll
    for (int ks = 0; ks < K / 32; ++ks) {
        const int kbase = ks * 32 + kgrp * 8;
        f16x8 a = *reinterpret_cast<const f16x8*>(&A[(size_t)(row0 + lrow) * K + kbase]);
        #pragma unroll
        for (int nt = 0; nt < NT; ++nt) {
            f16x8 b = *reinterpret_cast<const f16x8*>(&Wt[(size_t)(col0 + nt * 16 + lrow) * K + kbase]);
            acc[nt] = __builtin_amdgcn_mfma_f32_16x16x32_f16(a, b, acc[nt], 0, 0, 0);
        }
    }
    // C/D layout: col = lane&15, row = (lane>>4)*4 + r   [m89-verified]
    #pragma unroll
    for (int nt = 0; nt < NT; ++nt) {
        const int col = col0 + nt * 16 + lrow;
        float bb = (EPI == 0) ? bias[col] : 0.0f;
        #pragma unroll
        for (int r = 0; r < 4; ++r) {
            const int row = row0 + kgrp * 4 + r;
            float v = acc[nt][r];
            if (EPI == 0) v = fmaxf(v + bb, 0.0f);
            else          v = v * dis[row];
            C[(size_t)row * F + col] = __float2half(v);
        }
    }
}

// ---------------- gather: out[d] = dis[d]*(tab[d] + sum_{s in nbrs(d)} tab[s]) (+b) ----------------
template<bool BIAS, typename OutT>
__global__ __launch_bounds__(256) void gather64_kernel(const __half* __restrict__ tab,
                                                       const float* __restrict__ dis,
                                                       const float* __restrict__ b,
                                                       const int* __restrict__ row_start,
                                                       const int* __restrict__ csr_src,
                                                       OutT* __restrict__ out, int N) {
    const int node = blockIdx.x * 4 + (threadIdx.x >> 6);
    const int lane = threadIdx.x & 63;
    if (node >= N) return;
    const int beg = row_start[node], end = row_start[node + 1];
    float acc = __half2float(tab[(size_t)node * 64 + lane]);  // self loop (dis[s] folded in tab)
    float acc2 = 0.0f;
    int j = beg;
    for (; j + 7 < end; j += 8) {
        int s0 = csr_src[j],     s1 = csr_src[j + 1];
        int s2 = csr_src[j + 2], s3 = csr_src[j + 3];
        int s4 = csr_src[j + 4], s5 = csr_src[j + 5];
        int s6 = csr_src[j + 6], s7 = csr_src[j + 7];
        float v0 = __half2float(tab[(size_t)s0 * 64 + lane]);
        float v1 = __half2float(tab[(size_t)s1 * 64 + lane]);
        float v2 = __half2float(tab[(size_t)s2 * 64 + lane]);
        float v3 = __half2float(tab[(size_t)s3 * 64 + lane]);
        float v4 = __half2float(tab[(size_t)s4 * 64 + lane]);
        float v5 = __half2float(tab[(size_t)s5 * 64 + lane]);
        float v6 = __half2float(tab[(size_t)s6 * 64 + lane]);
        float v7 = __half2float(tab[(size_t)s7 * 64 + lane]);
        acc += v0; acc2 += v1; acc += v2; acc2 += v3;
        acc += v4; acc2 += v5; acc += v6; acc2 += v7;
    }
    for (; j < end; ++j) acc += __half2float(tab[(size_t)csr_src[j] * 64 + lane]);
    acc = (acc + acc2) * dis[node];
    if (BIAS) acc += b[lane];
    if constexpr (sizeof(OutT) == 2) out[(size_t)node * 64 + lane] = __float2half(acc);
    else                             out[(size_t)node * 64 + lane] = acc;
}

extern "C" void kernel_launch(void* const* d_in, const int* in_sizes, int n_in,
                              void* d_out, int out_size, void* d_ws, size_t ws_size,
                              hipStream_t stream) {
    const float* x  = (const float*)d_in[0];
    const int*   ei = (const int*)d_in[1];
    const float* W1 = (const float*)d_in[2];
    const float* b1 = (const float*)d_in[3];
    const float* W2 = (const float*)d_in[4];
    const float* b2 = (const float*)d_in[5];
    float* out = (float*)d_out;

    const int N = NN;
    const int E = in_sizes[1] / 2;
    const int* src = ei;
    const int* dst = ei + E;
    const int M = NB * NG;
    const int scan_blocks = (M + SCAN_B - 1) / SCAN_B;

    // workspace layout (4-byte words)
    int* counts    = (int*)d_ws;                 // M
    int* blk_sums  = counts + M;                 // 1024
    int* blk_off   = blk_sums + 1024;            // 1024
    int* row_start = blk_off + 1024;             // N+1 (+pad)
    float* dis     = (float*)(row_start + N + 64);
    int* staging   = (int*)(dis + N);            // E
    int* csr_src   = staging + E;                // E
    float* base    = (float*)(csr_src + E);
    __half* xh     = (__half*)base;                       // N*64 halves
    __half* aggh   = (__half*)(base + (size_t)N * 32);    // N*64 halves
    __half* zh     = (__half*)(base + (size_t)N * 64);    // N*64 halves
    __half* h1h    = (__half*)(base + (size_t)N * 96);    // N*128 halves
    __half* W1t    = (__half*)(base + (size_t)N * 160);   // 128*64 halves
    __half* W2t    = W1t + 128 * 64;                      // 64*128 halves

    // ---- CSR build (bucketed) ----
    bhist_kernel<<<NG, 256, 0, stream>>>(dst, counts, E);
    scan1_kernel<<<scan_blocks, SCAN_B, 0, stream>>>(counts, blk_sums, M);
    scan2_kernel<<<1, SCAN_B, 0, stream>>>(blk_sums, blk_off, scan_blocks);
    scan3_kernel<<<scan_blocks, SCAN_B, 0, stream>>>(counts, blk_off, M);
    bscatter_kernel<<<NG, 256, 0, stream>>>(src, dst, counts, staging, E);
    bfinal_kernel<<<NB, 256, 0, stream>>>(counts, staging, csr_src, row_start, dis, N, E);

    // ---- weight transposes to fp16 ----
    cvtWt_kernel<64, 128><<<(64 * 128 + 255) / 256, 256, 0, stream>>>(W1, W1t);
    cvtWt_kernel<128, 64><<<(128 * 64 + 255) / 256, 256, 0, stream>>>(W2, W2t);

    // ---- layer 1: xh = dis*x (fp16), aggh = A_hat-gather (fp16), h1h = relu(aggh@W1+b1) ----
    {
        long long n4 = (long long)N * 64 / 4;
        cvt_kernel<<<(int)((n4 + 255) / 256), 256, 0, stream>>>(x, dis, xh, n4);
    }
    gather64_kernel<false, __half><<<(N + 3) / 4, 256, 0, stream>>>(xh, dis, nullptr, row_start, csr_src, aggh, N);
    gemm_mfma_kernel<64, 128, 0><<<N / 32, 256, 0, stream>>>(aggh, W1t, b1, nullptr, h1h, N);

    // ---- layer 2: zh = (h1h@W2)*dis (fp16), out = A_hat-gather + b2 ----
    gemm_mfma_kernel<128, 64, 1><<<N / 32, 256, 0, stream>>>(h1h, W2t, nullptr, dis, zh, N);
    gather64_kernel<true, float><<<(N + 3) / 4, 256, 0, stream>>>(zh, dis, b2, row_start, csr_src, out, N);
}

// Round 7
// 191.944 us; speedup vs baseline: 2.3763x; 1.2407x over previous
//
#include <hip/hip_runtime.h>
#include <hip/hip_fp16.h>

#define NN 100000
#define NB 391        // ceil(NN/256) buckets of 256 dst nodes
#define NG 256        // edge-pass blocks
#define SCAN_B 256

using f16x8 = __attribute__((ext_vector_type(8))) _Float16;
using f32x4 = __attribute__((ext_vector_type(4))) float;

// ---------------- pass A: per-block bucket histogram (LDS) ----------------
__global__ __launch_bounds__(256) void bhist_kernel(const int* __restrict__ dst,
                                                    int* __restrict__ counts, int E) {
    __shared__ int h[NB];
    for (int i = threadIdx.x; i < NB; i += 256) h[i] = 0;
    __syncthreads();
    const int chunk = (E + NG - 1) / NG;
    const int lo = blockIdx.x * chunk, hi = min(E, lo + chunk);
    for (int e = lo + threadIdx.x; e < hi; e += 256) atomicAdd(&h[dst[e] >> 8], 1);
    __syncthreads();
    for (int i = threadIdx.x; i < NB; i += 256) counts[i * NG + blockIdx.x] = h[i];
}

// ---------------- in-place exclusive scan over counts[M] ----------------
__global__ void scan1_kernel(int* __restrict__ a, int* __restrict__ blk_sums, int M) {
    __shared__ int sm[SCAN_B];
    int t = threadIdx.x, i = blockIdx.x * SCAN_B + t;
    int v = (i < M) ? a[i] : 0;
    sm[t] = v; __syncthreads();
    for (int off = 1; off < SCAN_B; off <<= 1) {
        int x = (t >= off) ? sm[t - off] : 0; __syncthreads();
        sm[t] += x; __syncthreads();
    }
    if (i < M) a[i] = sm[t] - v;
    if (t == SCAN_B - 1) blk_sums[blockIdx.x] = sm[t];
}

__global__ void scan2_kernel(const int* __restrict__ blk_sums, int* __restrict__ blk_off, int nblk) {
    __shared__ int sm[SCAN_B];
    __shared__ int run;
    int t = threadIdx.x;
    if (t == 0) run = 0;
    __syncthreads();
    for (int base = 0; base < nblk; base += SCAN_B) {
        int i = base + t;
        int v = (i < nblk) ? blk_sums[i] : 0;
        sm[t] = v; __syncthreads();
        for (int off = 1; off < SCAN_B; off <<= 1) {
            int x = (t >= off) ? sm[t - off] : 0; __syncthreads();
            sm[t] += x; __syncthreads();
        }
        if (i < nblk) blk_off[i] = run + sm[t] - v;
        __syncthreads();
        if (t == 0) run += sm[SCAN_B - 1];
        __syncthreads();
    }
}

__global__ void scan3_kernel(int* __restrict__ a, const int* __restrict__ blk_off, int M) {
    int i = blockIdx.x * SCAN_B + threadIdx.x;
    if (i < M) a[i] += blk_off[blockIdx.x];
}

// ---------------- pass C: scatter edges into bucket-contiguous staging ----------------
__global__ __launch_bounds__(256) void bscatter_kernel(const int* __restrict__ src,
                                                       const int* __restrict__ dst,
                                                       const int* __restrict__ cstart,
                                                       int* __restrict__ staging, int E) {
    __shared__ int cur[NB];
    for (int i = threadIdx.x; i < NB; i += 256) cur[i] = cstart[i * NG + blockIdx.x];
    __syncthreads();
    const int chunk = (E + NG - 1) / NG;
    const int lo = blockIdx.x * chunk, hi = min(E, lo + chunk);
    for (int e = lo + threadIdx.x; e < hi; e += 256) {
        int d = dst[e];
        int pos = atomicAdd(&cur[d >> 8], 1);
        staging[pos] = src[e] | ((d & 255) << 17);
    }
}

// ---------------- pass D: per-bucket CSR finalize + row_start + dis ----------------
__global__ __launch_bounds__(256) void bfinal_kernel(const int* __restrict__ cstart,
                                                     const int* __restrict__ staging,
                                                     int* __restrict__ csr_src,
                                                     int* __restrict__ row_start,
                                                     float* __restrict__ dis, int N, int E) {
    __shared__ int h[256];
    __shared__ int sc[256];
    __shared__ int cur[256];
    const int b = blockIdx.x, t = threadIdx.x;
    const int base = cstart[b * NG];
    const int endb = (b == NB - 1) ? E : cstart[(b + 1) * NG];
    h[t] = 0; __syncthreads();
    for (int i = base + t; i < endb; i += 256) atomicAdd(&h[staging[i] >> 17], 1);
    __syncthreads();
    int v = h[t];
    sc[t] = v; __syncthreads();
    for (int off = 1; off < 256; off <<= 1) {
        int x = (t >= off) ? sc[t - off] : 0; __syncthreads();
        sc[t] += x; __syncthreads();
    }
    int excl = sc[t] - v;
    cur[t] = base + excl;
    int node = b * 256 + t;
    if (node < N) {
        row_start[node] = base + excl;
        dis[node] = rsqrtf((float)v + 1.0f);
    }
    if (b == NB - 1 && t == 0) row_start[N] = E;
    __syncthreads();
    for (int i = base + t; i < endb; i += 256) {
        int p = staging[i];
        int pos = atomicAdd(&cur[p >> 17], 1);
        csr_src[pos] = p & 0x1FFFF;
    }
}

// ---------------- fp32 -> fp16 table with dis premultiplied ----------------
__global__ void cvt_kernel(const float* __restrict__ in, const float* __restrict__ dis,
                           __half* __restrict__ out, long long n4) {
    long long i = (long long)blockIdx.x * blockDim.x + threadIdx.x;
    if (i >= n4) return;
    float4 v = ((const float4*)in)[i];
    float w = dis[(int)(i >> 4)];
    __half2* o = (__half2*)out;
    o[2 * i]     = __floats2half2_rn(v.x * w, v.y * w);
    o[2 * i + 1] = __floats2half2_rn(v.z * w, v.w * w);
}

// ---------------- W[K,F] fp32 -> Wt[F,K] fp16 ----------------
template<int K, int F>
__global__ void cvtWt_kernel(const float* __restrict__ W, __half* __restrict__ Wt) {
    int i = blockIdx.x * 256 + threadIdx.x;
    if (i >= K * F) return;
    int k = i / F, c = i % F;
    Wt[c * K + k] = __float2half(W[i]);
}

// ---------------- MFMA GEMM: C[N,F](fp16) = A[N,K](fp16) @ Wt[F,K]^T, epilogue ----------------
// EPI 0: relu(acc + bias[col]); EPI 1: acc * dis[row]
template<int K, int F, int EPI>
__global__ __launch_bounds__(256) void gemm_mfma_kernel(const __half* __restrict__ A,
                                                        const __half* __restrict__ Wt,
                                                        const float* __restrict__ bias,
                                                        const float* __restrict__ dis,
                                                        __half* __restrict__ C, int N) {
    constexpr int BM = 32;
    constexpr int NT = F / 32;
    const int wid  = threadIdx.x >> 6;
    const int lane = threadIdx.x & 63;
    const int wr = wid >> 1;
    const int wc = wid & 1;
    const int row0 = blockIdx.x * BM + wr * 16;
    const int col0 = wc * (F / 2);
    const int lrow = lane & 15;
    const int kgrp = lane >> 4;

    f32x4 acc[NT];
    #pragma unroll
    for (int nt = 0; nt < NT; ++nt) acc[nt] = (f32x4){0.f, 0.f, 0.f, 0.f};

    #pragma unroll
    for (int ks = 0; ks < K / 32; ++ks) {
        const int kbase = ks * 32 + kgrp * 8;
        f16x8 a = *reinterpret_cast<const f16x8*>(&A[(size_t)(row0 + lrow) * K + kbase]);
        #pragma unroll
        for (int nt = 0; nt < NT; ++nt) {
            f16x8 b = *reinterpret_cast<const f16x8*>(&Wt[(size_t)(col0 + nt * 16 + lrow) * K + kbase]);
            acc[nt] = __builtin_amdgcn_mfma_f32_16x16x32_f16(a, b, acc[nt], 0, 0, 0);
        }
    }
    #pragma unroll
    for (int nt = 0; nt < NT; ++nt) {
        const int col = col0 + nt * 16 + lrow;
        float bb = (EPI == 0) ? bias[col] : 0.0f;
        #pragma unroll
        for (int r = 0; r < 4; ++r) {
            const int row = row0 + kgrp * 4 + r;
            float v = acc[nt][r];
            if (EPI == 0) v = fmaxf(v + bb, 0.0f);
            else          v = v * dis[row];
            C[(size_t)row * F + col] = __float2half(v);
        }
    }
}

// ---------------- gather v2: 1 wave/node, 8 edges per step, 16 B/lane ----------------
// lane = g*8 + sub (g = edge slot 0..7, sub = col-octet 0..7)
// out[d][c] = dis[d]*(tab[d][c] + sum_{s in nbrs(d)} tab[s][c]) (+b[c])
template<bool BIAS, typename OutT>
__global__ __launch_bounds__(256) void gather64v2_kernel(const __half* __restrict__ tab,
                                                         const float* __restrict__ dis,
                                                         const float* __restrict__ b,
                                                         const int* __restrict__ row_start,
                                                         const int* __restrict__ csr_src,
                                                         OutT* __restrict__ out, int N) {
    const int node = blockIdx.x * 4 + (threadIdx.x >> 6);
    const int lane = threadIdx.x & 63;
    const int g   = lane >> 3;    // edge slot within step
    const int sub = lane & 7;     // column octet
    if (node >= N) return;
    const int beg = row_start[node], end = row_start[node + 1];

    float acc[8];
    {   // self-loop row counted once via group 0
        f16x8 sv = *reinterpret_cast<const f16x8*>(&tab[(size_t)node * 64 + sub * 8]);
        #pragma unroll
        for (int q = 0; q < 8; ++q) acc[q] = (g == 0) ? (float)sv[q] : 0.0f;
    }

    int j = beg;
    #pragma unroll 2
    for (; j + 8 <= end; j += 8) {          // full steps: no divergence
        int s = csr_src[j + g];
        f16x8 v = *reinterpret_cast<const f16x8*>(&tab[(size_t)s * 64 + sub * 8]);
        #pragma unroll
        for (int q = 0; q < 8; ++q) acc[q] += (float)v[q];
    }
    if (j + g < end) {                       // tail: exec-masked groups
        int s = csr_src[j + g];
        f16x8 v = *reinterpret_cast<const f16x8*>(&tab[(size_t)s * 64 + sub * 8]);
        #pragma unroll
        for (int q = 0; q < 8; ++q) acc[q] += (float)v[q];
    }

    // butterfly-reduce across the 8 edge slots (lane bits 3..5)
    #pragma unroll
    for (int q = 0; q < 8; ++q) {
        acc[q] += __shfl_xor(acc[q], 8);
        acc[q] += __shfl_xor(acc[q], 16);
        acc[q] += __shfl_xor(acc[q], 32);
    }

    if (g == 0) {
        const float dd = dis[node];
        if constexpr (sizeof(OutT) == 2) {
            f16x8 o;
            #pragma unroll
            for (int q = 0; q < 8; ++q) {
                float v = acc[q] * dd;
                if (BIAS) v += b[sub * 8 + q];
                o[q] = (_Float16)v;
            }
            *reinterpret_cast<f16x8*>(&out[(size_t)node * 64 + sub * 8]) = o;
        } else {
            float4 o0, o1;
            float vv[8];
            #pragma unroll
            for (int q = 0; q < 8; ++q) {
                float v = acc[q] * dd;
                if (BIAS) v += b[sub * 8 + q];
                vv[q] = v;
            }
            o0 = make_float4(vv[0], vv[1], vv[2], vv[3]);
            o1 = make_float4(vv[4], vv[5], vv[6], vv[7]);
            float* op = (float*)&out[(size_t)node * 64 + sub * 8];
            *reinterpret_cast<float4*>(op)     = o0;
            *reinterpret_cast<float4*>(op + 4) = o1;
        }
    }
}

extern "C" void kernel_launch(void* const* d_in, const int* in_sizes, int n_in,
                              void* d_out, int out_size, void* d_ws, size_t ws_size,
                              hipStream_t stream) {
    const float* x  = (const float*)d_in[0];
    const int*   ei = (const int*)d_in[1];
    const float* W1 = (const float*)d_in[2];
    const float* b1 = (const float*)d_in[3];
    const float* W2 = (const float*)d_in[4];
    const float* b2 = (const float*)d_in[5];
    float* out = (float*)d_out;

    const int N = NN;
    const int E = in_sizes[1] / 2;
    const int* src = ei;
    const int* dst = ei + E;
    const int M = NB * NG;
    const int scan_blocks = (M + SCAN_B - 1) / SCAN_B;

    // workspace layout (4-byte words)
    int* counts    = (int*)d_ws;                 // M
    int* blk_sums  = counts + M;                 // 1024
    int* blk_off   = blk_sums + 1024;            // 1024
    int* row_start = blk_off + 1024;             // N+1 (+pad)
    float* dis     = (float*)(row_start + N + 64);
    int* staging   = (int*)(dis + N);            // E
    int* csr_src   = staging + E;                // E
    float* base    = (float*)(csr_src + E);
    __half* xh     = (__half*)base;                       // N*64 halves
    __half* aggh   = (__half*)(base + (size_t)N * 32);    // N*64 halves
    __half* zh     = (__half*)(base + (size_t)N * 64);    // N*64 halves
    __half* h1h    = (__half*)(base + (size_t)N * 96);    // N*128 halves
    __half* W1t    = (__half*)(base + (size_t)N * 160);   // 128*64 halves
    __half* W2t    = W1t + 128 * 64;                      // 64*128 halves

    // ---- CSR build (bucketed) ----
    bhist_kernel<<<NG, 256, 0, stream>>>(dst, counts, E);
    scan1_kernel<<<scan_blocks, SCAN_B, 0, stream>>>(counts, blk_sums, M);
    scan2_kernel<<<1, SCAN_B, 0, stream>>>(blk_sums, blk_off, scan_blocks);
    scan3_kernel<<<scan_blocks, SCAN_B, 0, stream>>>(counts, blk_off, M);
    bscatter_kernel<<<NG, 256, 0, stream>>>(src, dst, counts, staging, E);
    bfinal_kernel<<<NB, 256, 0, stream>>>(counts, staging, csr_src, row_start, dis, N, E);

    // ---- weight transposes to fp16 ----
    cvtWt_kernel<64, 128><<<(64 * 128 + 255) / 256, 256, 0, stream>>>(W1, W1t);
    cvtWt_kernel<128, 64><<<(128 * 64 + 255) / 256, 256, 0, stream>>>(W2, W2t);

    // ---- layer 1: xh = dis*x (fp16), aggh = A_hat-gather (fp16), h1h = relu(aggh@W1+b1) ----
    {
        long long n4 = (long long)N * 64 / 4;
        cvt_kernel<<<(int)((n4 + 255) / 256), 256, 0, stream>>>(x, dis, xh, n4);
    }
    gather64v2_kernel<false, __half><<<(N + 3) / 4, 256, 0, stream>>>(xh, dis, nullptr, row_start, csr_src, aggh, N);
    gemm_mfma_kernel<64, 128, 0><<<N / 32, 256, 0, stream>>>(aggh, W1t, b1, nullptr, h1h, N);

    // ---- layer 2: zh = (h1h@W2)*dis (fp16), out = A_hat-gather + b2 ----
    gemm_mfma_kernel<128, 64, 1><<<N / 32, 256, 0, stream>>>(h1h, W2t, nullptr, dis, zh, N);
    gather64v2_kernel<true, float><<<(N + 3) / 4, 256, 0, stream>>>(zh, dis, b2, row_start, csr_src, out, N);
}

// Round 8
// 189.358 us; speedup vs baseline: 2.4087x; 1.0137x over previous
//
#include <hip/hip_runtime.h>
#include <hip/hip_fp16.h>

#define NN 100000
#define NB 391        // ceil(NN/256) buckets of 256 dst nodes
#define NG 256        // edge-pass blocks
#define SCAN_B 256

using f16x8 = __attribute__((ext_vector_type(8))) _Float16;
using f32x4 = __attribute__((ext_vector_type(4))) float;

// ---------------- pass A: per-block bucket histogram (LDS) ----------------
__global__ __launch_bounds__(256) void bhist_kernel(const int* __restrict__ dst,
                                                    int* __restrict__ counts, int E) {
    __shared__ int h[NB];
    for (int i = threadIdx.x; i < NB; i += 256) h[i] = 0;
    __syncthreads();
    const int chunk = (E + NG - 1) / NG;
    const int lo = blockIdx.x * chunk, hi = min(E, lo + chunk);
    for (int e = lo + threadIdx.x; e < hi; e += 256) atomicAdd(&h[dst[e] >> 8], 1);
    __syncthreads();
    for (int i = threadIdx.x; i < NB; i += 256) counts[i * NG + blockIdx.x] = h[i];
}

// ---------------- in-place exclusive scan over counts[M] ----------------
__global__ void scan1_kernel(int* __restrict__ a, int* __restrict__ blk_sums, int M) {
    __shared__ int sm[SCAN_B];
    int t = threadIdx.x, i = blockIdx.x * SCAN_B + t;
    int v = (i < M) ? a[i] : 0;
    sm[t] = v; __syncthreads();
    for (int off = 1; off < SCAN_B; off <<= 1) {
        int x = (t >= off) ? sm[t - off] : 0; __syncthreads();
        sm[t] += x; __syncthreads();
    }
    if (i < M) a[i] = sm[t] - v;
    if (t == SCAN_B - 1) blk_sums[blockIdx.x] = sm[t];
}

__global__ void scan2_kernel(const int* __restrict__ blk_sums, int* __restrict__ blk_off, int nblk) {
    __shared__ int sm[SCAN_B];
    __shared__ int run;
    int t = threadIdx.x;
    if (t == 0) run = 0;
    __syncthreads();
    for (int base = 0; base < nblk; base += SCAN_B) {
        int i = base + t;
        int v = (i < nblk) ? blk_sums[i] : 0;
        sm[t] = v; __syncthreads();
        for (int off = 1; off < SCAN_B; off <<= 1) {
            int x = (t >= off) ? sm[t - off] : 0; __syncthreads();
            sm[t] += x; __syncthreads();
        }
        if (i < nblk) blk_off[i] = run + sm[t] - v;
        __syncthreads();
        if (t == 0) run += sm[SCAN_B - 1];
        __syncthreads();
    }
}

__global__ void scan3_kernel(int* __restrict__ a, const int* __restrict__ blk_off, int M) {
    int i = blockIdx.x * SCAN_B + threadIdx.x;
    if (i < M) a[i] += blk_off[blockIdx.x];
}

// ---------------- pass C: scatter edges into bucket-contiguous staging ----------------
__global__ __launch_bounds__(256) void bscatter_kernel(const int* __restrict__ src,
                                                       const int* __restrict__ dst,
                                                       const int* __restrict__ cstart,
                                                       int* __restrict__ staging, int E) {
    __shared__ int cur[NB];
    for (int i = threadIdx.x; i < NB; i += 256) cur[i] = cstart[i * NG + blockIdx.x];
    __syncthreads();
    const int chunk = (E + NG - 1) / NG;
    const int lo = blockIdx.x * chunk, hi = min(E, lo + chunk);
    for (int e = lo + threadIdx.x; e < hi; e += 256) {
        int d = dst[e];
        int pos = atomicAdd(&cur[d >> 8], 1);
        staging[pos] = src[e] | ((d & 255) << 17);
    }
}

// ---------------- pass D: per-bucket CSR finalize + row_start + dis + x->fp16 cvt ----------------
__global__ __launch_bounds__(256) void bfinal_kernel(const int* __restrict__ cstart,
                                                     const int* __restrict__ staging,
                                                     int* __restrict__ csr_src,
                                                     int* __restrict__ row_start,
                                                     float* __restrict__ dis,
                                                     const float* __restrict__ x,
                                                     __half* __restrict__ xh,
                                                     int N, int E) {
    __shared__ int h[256];
    __shared__ int sc[256];
    __shared__ int cur[256];
    __shared__ float sdis[256];
    const int b = blockIdx.x, t = threadIdx.x;
    const int base = cstart[b * NG];
    const int endb = (b == NB - 1) ? E : cstart[(b + 1) * NG];
    h[t] = 0; __syncthreads();
    for (int i = base + t; i < endb; i += 256) atomicAdd(&h[staging[i] >> 17], 1);
    __syncthreads();
    int v = h[t];
    sc[t] = v; __syncthreads();
    for (int off = 1; off < 256; off <<= 1) {
        int xv = (t >= off) ? sc[t - off] : 0; __syncthreads();
        sc[t] += xv; __syncthreads();
    }
    int excl = sc[t] - v;
    cur[t] = base + excl;
    float dv = rsqrtf((float)v + 1.0f);
    sdis[t] = dv;
    int node = b * 256 + t;
    if (node < N) {
        row_start[node] = base + excl;
        dis[node] = dv;
    }
    if (b == NB - 1 && t == 0) row_start[N] = E;
    __syncthreads();
    // scatter within bucket -> final CSR
    for (int i = base + t; i < endb; i += 256) {
        int p = staging[i];
        int pos = atomicAdd(&cur[p >> 17], 1);
        csr_src[pos] = p & 0x1FFFF;
    }
    // fused: xh[node] = dis[node] * x[node]  (fp16), 256 nodes x 16 float4-chunks
    const int node0 = b * 256;
    const int nmax = min(256, N - node0);
    for (int i = t; i < nmax * 16; i += 256) {
        int nl = i >> 4, c4 = i & 15;
        float4 vx = ((const float4*)x)[((size_t)(node0 + nl) * 64 + c4 * 4) >> 2];
        float w = sdis[nl];
        __half2* o = (__half2*)&xh[(size_t)(node0 + nl) * 64 + c4 * 4];
        o[0] = __floats2half2_rn(vx.x * w, vx.y * w);
        o[1] = __floats2half2_rn(vx.z * w, vx.w * w);
    }
}

// ---------------- W[K,F] fp32 -> Wt[F,K] fp16 ----------------
template<int K, int F>
__global__ void cvtWt_kernel(const float* __restrict__ W, __half* __restrict__ Wt) {
    int i = blockIdx.x * 256 + threadIdx.x;
    if (i >= K * F) return;
    int k = i / F, c = i % F;
    Wt[c * K + k] = __float2half(W[i]);
}

// ---------------- MFMA GEMM: C[N,F](fp16) = A[N,K](fp16) @ Wt[F,K]^T, epilogue ----------------
// EPI 0: relu(acc + bias[col]); EPI 1: acc * dis[row]
template<int K, int F, int EPI>
__global__ __launch_bounds__(256) void gemm_mfma_kernel(const __half* __restrict__ A,
                                                        const __half* __restrict__ Wt,
                                                        const float* __restrict__ bias,
                                                        const float* __restrict__ dis,
                                                        __half* __restrict__ C, int N) {
    constexpr int BM = 32;
    constexpr int NT = F / 32;
    const int wid  = threadIdx.x >> 6;
    const int lane = threadIdx.x & 63;
    const int wr = wid >> 1;
    const int wc = wid & 1;
    const int row0 = blockIdx.x * BM + wr * 16;
    const int col0 = wc * (F / 2);
    const int lrow = lane & 15;
    const int kgrp = lane >> 4;

    f32x4 acc[NT];
    #pragma unroll
    for (int nt = 0; nt < NT; ++nt) acc[nt] = (f32x4){0.f, 0.f, 0.f, 0.f};

    #pragma unroll
    for (int ks = 0; ks < K / 32; ++ks) {
        const int kbase = ks * 32 + kgrp * 8;
        f16x8 a = *reinterpret_cast<const f16x8*>(&A[(size_t)(row0 + lrow) * K + kbase]);
        #pragma unroll
        for (int nt = 0; nt < NT; ++nt) {
            f16x8 b = *reinterpret_cast<const f16x8*>(&Wt[(size_t)(col0 + nt * 16 + lrow) * K + kbase]);
            acc[nt] = __builtin_amdgcn_mfma_f32_16x16x32_f16(a, b, acc[nt], 0, 0, 0);
        }
    }
    #pragma unroll
    for (int nt = 0; nt < NT; ++nt) {
        const int col = col0 + nt * 16 + lrow;
        float bb = (EPI == 0) ? bias[col] : 0.0f;
        #pragma unroll
        for (int r = 0; r < 4; ++r) {
            const int row = row0 + kgrp * 4 + r;
            float v = acc[nt][r];
            if (EPI == 0) v = fmaxf(v + bb, 0.0f);
            else          v = v * dis[row];
            C[(size_t)row * F + col] = __float2half(v);
        }
    }
}

// ---------------- gather v3: 1 wave/node, 16 edges per iter (2 pipelined steps), fma_mix accum ----------------
// lane = g*8 + sub (g = edge slot 0..7, sub = col-octet 0..7)
template<bool BIAS, typename OutT>
__global__ __launch_bounds__(256) void gather64v3_kernel(const __half* __restrict__ tab,
                                                         const float* __restrict__ dis,
                                                         const float* __restrict__ b,
                                                         const int* __restrict__ row_start,
                                                         const int* __restrict__ csr_src,
                                                         OutT* __restrict__ out, int N,
                                                         float one) {
    const int node = blockIdx.x * 4 + (threadIdx.x >> 6);
    const int lane = threadIdx.x & 63;
    const int g   = lane >> 3;
    const int sub = lane & 7;
    if (node >= N) return;
    const int beg = row_start[node], end = row_start[node + 1];

    float acc[8];
    {   // self-loop row counted once via group 0
        f16x8 sv = *reinterpret_cast<const f16x8*>(&tab[(size_t)node * 64 + sub * 8]);
        #pragma unroll
        for (int q = 0; q < 8; ++q) acc[q] = (g == 0) ? (float)sv[q] : 0.0f;
    }

    int j = beg;
    for (; j + 16 <= end; j += 16) {
        int sA = csr_src[j + g];
        int sB = csr_src[j + 8 + g];
        f16x8 vA = *reinterpret_cast<const f16x8*>(&tab[(size_t)sA * 64 + sub * 8]);
        f16x8 vB = *reinterpret_cast<const f16x8*>(&tab[(size_t)sB * 64 + sub * 8]);
        #pragma unroll
        for (int q = 0; q < 8; ++q) acc[q] = fmaf((float)vA[q], one, acc[q]);
        #pragma unroll
        for (int q = 0; q < 8; ++q) acc[q] = fmaf((float)vB[q], one, acc[q]);
    }
    if (j + 8 <= end) {
        int s = csr_src[j + g];
        f16x8 v = *reinterpret_cast<const f16x8*>(&tab[(size_t)s * 64 + sub * 8]);
        #pragma unroll
        for (int q = 0; q < 8; ++q) acc[q] = fmaf((float)v[q], one, acc[q]);
        j += 8;
    }
    if (j + g < end) {                       // tail: exec-masked groups
        int s = csr_src[j + g];
        f16x8 v = *reinterpret_cast<const f16x8*>(&tab[(size_t)s * 64 + sub * 8]);
        #pragma unroll
        for (int q = 0; q < 8; ++q) acc[q] = fmaf((float)v[q], one, acc[q]);
    }

    // butterfly-reduce across the 8 edge slots (lane bits 3..5)
    #pragma unroll
    for (int q = 0; q < 8; ++q) {
        acc[q] += __shfl_xor(acc[q], 8);
        acc[q] += __shfl_xor(acc[q], 16);
        acc[q] += __shfl_xor(acc[q], 32);
    }

    if (g == 0) {
        const float dd = dis[node];
        if constexpr (sizeof(OutT) == 2) {
            f16x8 o;
            #pragma unroll
            for (int q = 0; q < 8; ++q) {
                float v = acc[q] * dd;
                if (BIAS) v += b[sub * 8 + q];
                o[q] = (_Float16)v;
            }
            *reinterpret_cast<f16x8*>(&out[(size_t)node * 64 + sub * 8]) = o;
        } else {
            float vv[8];
            #pragma unroll
            for (int q = 0; q < 8; ++q) {
                float v = acc[q] * dd;
                if (BIAS) v += b[sub * 8 + q];
                vv[q] = v;
            }
            float* op = (float*)&out[(size_t)node * 64 + sub * 8];
            *reinterpret_cast<float4*>(op)     = make_float4(vv[0], vv[1], vv[2], vv[3]);
            *reinterpret_cast<float4*>(op + 4) = make_float4(vv[4], vv[5], vv[6], vv[7]);
        }
    }
}

extern "C" void kernel_launch(void* const* d_in, const int* in_sizes, int n_in,
                              void* d_out, int out_size, void* d_ws, size_t ws_size,
                              hipStream_t stream) {
    const float* x  = (const float*)d_in[0];
    const int*   ei = (const int*)d_in[1];
    const float* W1 = (const float*)d_in[2];
    const float* b1 = (const float*)d_in[3];
    const float* W2 = (const float*)d_in[4];
    const float* b2 = (const float*)d_in[5];
    float* out = (float*)d_out;

    const int N = NN;
    const int E = in_sizes[1] / 2;
    const int* src = ei;
    const int* dst = ei + E;
    const int M = NB * NG;
    const int scan_blocks = (M + SCAN_B - 1) / SCAN_B;

    // workspace layout (4-byte words)
    int* counts    = (int*)d_ws;                 // M
    int* blk_sums  = counts + M;                 // 1024
    int* blk_off   = blk_sums + 1024;            // 1024
    int* row_start = blk_off + 1024;             // N+1 (+pad)
    float* dis     = (float*)(row_start + N + 64);
    int* staging   = (int*)(dis + N);            // E
    int* csr_src   = staging + E;                // E
    float* base    = (float*)(csr_src + E);
    __half* xh     = (__half*)base;                       // N*64 halves
    __half* aggh   = (__half*)(base + (size_t)N * 32);    // N*64 halves
    __half* zh     = (__half*)(base + (size_t)N * 64);    // N*64 halves
    __half* h1h    = (__half*)(base + (size_t)N * 96);    // N*128 halves
    __half* W1t    = (__half*)(base + (size_t)N * 160);   // 128*64 halves
    __half* W2t    = W1t + 128 * 64;                      // 64*128 halves

    // ---- CSR build (bucketed) + fused dis/x-cvt ----
    bhist_kernel<<<NG, 256, 0, stream>>>(dst, counts, E);
    scan1_kernel<<<scan_blocks, SCAN_B, 0, stream>>>(counts, blk_sums, M);
    scan2_kernel<<<1, SCAN_B, 0, stream>>>(blk_sums, blk_off, scan_blocks);
    scan3_kernel<<<scan_blocks, SCAN_B, 0, stream>>>(counts, blk_off, M);
    bscatter_kernel<<<NG, 256, 0, stream>>>(src, dst, counts, staging, E);
    bfinal_kernel<<<NB, 256, 0, stream>>>(counts, staging, csr_src, row_start, dis, x, xh, N, E);

    // ---- weight transposes to fp16 ----
    cvtWt_kernel<64, 128><<<(64 * 128 + 255) / 256, 256, 0, stream>>>(W1, W1t);
    cvtWt_kernel<128, 64><<<(128 * 64 + 255) / 256, 256, 0, stream>>>(W2, W2t);

    // ---- layer 1: aggh = A_hat-gather(xh) (fp16), h1h = relu(aggh@W1+b1) ----
    gather64v3_kernel<false, __half><<<(N + 3) / 4, 256, 0, stream>>>(xh, dis, nullptr, row_start, csr_src, aggh, N, 1.0f);
    gemm_mfma_kernel<64, 128, 0><<<N / 32, 256, 0, stream>>>(aggh, W1t, b1, nullptr, h1h, N);

    // ---- layer 2: zh = (h1h@W2)*dis (fp16), out = A_hat-gather(zh) + b2 ----
    gemm_mfma_kernel<128, 64, 1><<<N / 32, 256, 0, stream>>>(h1h, W2t, nullptr, dis, zh, N);
    gather64v3_kernel<true, float><<<(N + 3) / 4, 256, 0, stream>>>(zh, dis, b2, row_start, csr_src, out, N, 1.0f);
}